// Round 7
// baseline (6192.112 us; speedup 1.0000x reference)
//
#include <hip/hip_runtime.h>
#include <hip/hip_bf16.h>

// ---------------------------------------------------------------------------
// DEQ layer, MI355X round 6.
//  - Round-6 persistent kernel REVERTED: device-scope fences in the grid
//    barrier force L2 wb+inv per phase (FETCH 1.05 GB measured) -> 2.6x loss.
//  - This round: multi-kernel (kernel boundary = cheap HW coherence) with
//    dispatch-count collapse 119 -> 52 via row-private fusion:
//      * gemm2a: gemm2 (BN=256, block owns full F rows) + fused Anderson(t+1)
//        for its own rows (history row-private; fresh F via LDS) + warm-up
//        modes. Slot-redirect pos2->1 encodes X2===X1, F2===F1 exactly.
//      * chain_kernel: colsum + 21 damped Gram matvecs + sigma in ONE 1-block
//        kernel (round-5 arithmetic preserved).
//  - gemm1 (verified bf16 MFMA) and gram (verified) unchanged.
// ---------------------------------------------------------------------------

#define B_ROWS 2048
#define D_LAT  256
#define D_CTX  256
#define D_HID  1024
#define KCAT   512
#define SLOT   (B_ROWS * D_LAT)
#define NRING  7

typedef __bf16 bf16x8 __attribute__((ext_vector_type(8)));
typedef float f32x4 __attribute__((ext_vector_type(4)));
typedef unsigned short u16;

// slot map with warm-up dedup: position p lives in slot p%7, except the
// phantom position 2 (X2===X1, F2===F1) which redirects to slot 1.
__device__ __forceinline__ int rdslot(int p) { return (p == 2) ? 1 : (p % NRING); }

// ---------------- init: zc=[0|bf16(ctx)], G=0, X slot0 = 0 -----------------
__global__ void init_kernel(const float* __restrict__ ctx,
                            __hip_bfloat16* __restrict__ zc,
                            float* __restrict__ G1p, float* __restrict__ G2,
                            float* __restrict__ Xh) {
  int i = blockIdx.x * 256 + threadIdx.x;
  if (i < B_ROWS * KCAT) {
    int b = i >> 9, c = i & 511;
    float v = (c < 256) ? 0.0f : ctx[b * 256 + (c - 256)];
    zc[i] = __float2bfloat16(v);
  }
  if (i < 512 * 512) G1p[i] = 0.0f;
  if (i < 256 * 256) G2[i] = 0.0f;
  if (i < SLOT) Xh[i] = 0.0f;
}

// ---------------- Gram build, split-K x8, atomic accumulate (verified) -----
__global__ __launch_bounds__(256) void gram_kernel(
    const float* __restrict__ W1, const float* __restrict__ W2,
    float* __restrict__ G1p, float* __restrict__ G2) {
  __shared__ float As[32][65];
  __shared__ float Bs[32][65];
  const int tid = threadIdx.x;
  const int tx = tid & 15, ty = tid >> 4;

  const float* X; float* G; int N, ti, tj, k0base; bool modeA;
  int b = blockIdx.x;
  if (b < 512) {
    modeA = true; X = W1; G = G1p; N = 512;
    int s = b >> 6, t = b & 63;
    ti = t >> 3; tj = t & 7; k0base = s * 128;
  } else {
    modeA = false; b -= 512; X = W2; G = G2; N = 256;
    int s = b >> 4, t = b & 15;
    ti = t >> 2; tj = t & 3; k0base = s * 128;
  }

  float acc[4][4] = {};
  for (int k0 = k0base; k0 < k0base + 128; k0 += 32) {
    if (modeA) {
      for (int idx = tid; idx < 2048; idx += 256) {
        int r = idx & 63, c = idx >> 6;
        As[c][r] = X[(size_t)(k0 + c) * 512 + ti * 64 + r];
        Bs[c][r] = X[(size_t)(k0 + c) * 512 + tj * 64 + r];
      }
    } else {
      for (int idx = tid; idx < 2048; idx += 256) {
        int c = idx & 31, r = idx >> 5;
        As[c][r] = X[(size_t)(ti * 64 + r) * 1024 + k0 + c];
        Bs[c][r] = X[(size_t)(tj * 64 + r) * 1024 + k0 + c];
      }
    }
    __syncthreads();
#pragma unroll
    for (int kk = 0; kk < 32; kk++) {
      float a[4], bb[4];
#pragma unroll
      for (int i = 0; i < 4; i++) a[i] = As[kk][ty * 4 + i];
#pragma unroll
      for (int j = 0; j < 4; j++) bb[j] = Bs[kk][tx * 4 + j];
#pragma unroll
      for (int i = 0; i < 4; i++)
#pragma unroll
        for (int j = 0; j < 4; j++) acc[i][j] += a[i] * bb[j];
    }
    __syncthreads();
  }
#pragma unroll
  for (int i = 0; i < 4; i++)
#pragma unroll
    for (int j = 0; j < 4; j++)
      atomicAdd(&G[(size_t)(ti * 64 + ty * 4 + i) * N + tj * 64 + tx * 4 + j],
                acc[i][j]);
}

// ---------------- whole damped power chain + sigma, ONE block --------------
__global__ __launch_bounds__(1024) void chain_kernel(
    const float* __restrict__ W1, const float* __restrict__ G1p,
    const float* __restrict__ G2, float* __restrict__ sig) {
  __shared__ float va[512], vb[512], ua[256], ub[256];
  __shared__ float ps[1024];
  __shared__ float red[16];
  const int tid = threadIdx.x;
  const int lane = tid & 63, w = tid >> 6;

  // colsum: v1 = W1^T ones (split rows into 2 halves across the 1024 threads)
  {
    int j = tid & 511, h = tid >> 9;
    float s = 0.f;
    for (int r = h * 512; r < h * 512 + 512; r++)
      s += W1[(size_t)r * 512 + j];
    ps[tid] = s;
  }
  if (tid < 256) ua[tid] = 1.0f;
  __syncthreads();
  if (tid < 512) va[tid] = ps[tid] + ps[tid + 512];
  __syncthreads();

  float *vc = va, *vn = vb, *uc = ua, *un = ub;
  for (int it = 1; it <= 21; it++) {
    if (w >= 8) {  // G2 side: 8 waves x 32 rows
      for (int rr = 0; rr < 32; rr++) {
        int r = (w - 8) * 32 + rr;
        const float4* Gr = (const float4*)(G2 + (size_t)r * 256);
        float4 g = Gr[lane];
        float4 u = ((const float4*)uc)[lane];
        float acc = g.x * u.x + g.y * u.y + g.z * u.z + g.w * u.w;
        for (int off = 32; off; off >>= 1) acc += __shfl_down(acc, off, 64);
        if (lane == 0) un[r] = 0.25f * acc;
      }
    } else if (it >= 2) {  // G1' side: 8 waves x 64 rows (active from it=2)
      for (int rr = 0; rr < 64; rr++) {
        int r = w * 64 + rr;
        const float4* Gr = (const float4*)(G1p + (size_t)r * 512);
        float acc = 0.f;
#pragma unroll
        for (int c = 0; c < 2; c++) {
          float4 g = Gr[lane + 64 * c];
          float4 u = ((const float4*)vc)[lane + 64 * c];
          acc += g.x * u.x + g.y * u.y + g.z * u.z + g.w * u.w;
        }
        for (int off = 32; off; off >>= 1) acc += __shfl_down(acc, off, 64);
        if (lane == 0) vn[r] = 0.25f * acc;
      }
    }
    __syncthreads();
    { float* t = uc; uc = un; un = t; }
    if (it >= 2) { float* t = vc; vc = vn; vn = t; }
    __syncthreads();
  }
  // uc=u21, un=u20; vc=v21, vn=v20. Four dots -> sigma (round-5 formulas).
  float d[4];
  for (int k = 0; k < 4; k++) {
    float s = 0.f;
    if (k == 0) { for (int i = tid; i < 512; i += 1024) s += vc[i] * vn[i]; }
    if (k == 1) { for (int i = tid; i < 512; i += 1024) s += vc[i] * vc[i]; }
    if (k == 2) { for (int i = tid; i < 256; i += 1024) s += un[i] * un[i]; }
    if (k == 3) { for (int i = tid; i < 256; i += 1024) s += un[i] * uc[i]; }
    for (int off = 32; off; off >>= 1) s += __shfl_down(s, off, 64);
    if (lane == 0) red[w] = s;
    __syncthreads();
    if (tid == 0) {
      float t = 0.f;
      for (int q = 0; q < 16; q++) t += red[q];
      ps[k] = t;  // stash
    }
    __syncthreads();
    d[k] = ps[k];
  }
  if (tid == 0) {
    sig[0] = sqrtf(0.25f * d[0] / d[1]);
    sig[1] = sqrtf(0.25f * d[2] / d[3]);
  }
}

// ---------------- fold sigma into bf16 weights -----------------------------
__global__ void wfold_kernel(const float* __restrict__ W1,
                             const float* __restrict__ W2,
                             const float* __restrict__ sig,
                             __hip_bfloat16* __restrict__ W1b,
                             __hip_bfloat16* __restrict__ W2b) {
  int i = blockIdx.x * 256 + threadIdx.x;
  if (i < D_HID * KCAT) W1b[i] = __float2bfloat16(W1[i] * sig[0]);
  int j = i - D_HID * KCAT;
  if (j >= 0 && j < D_LAT * D_HID) W2b[j] = __float2bfloat16(W2[j] * sig[1]);
}

// ---------------- bf16 MFMA GEMM1: hb = tanh(zc @ W1b^T + b1) (verified) ---
template <int BM, int BN, bool OUT_BF16>
__global__ __launch_bounds__(256) void gemm_mfma(
    const __hip_bfloat16* __restrict__ A, const __hip_bfloat16* __restrict__ W,
    int K, const float* __restrict__ bias, float* __restrict__ Cf,
    __hip_bfloat16* __restrict__ Cb, int N) {
  __shared__ __align__(16) u16 lds[(BM + BN) * 64];
  u16* As = lds;
  u16* Ws = lds + BM * 64;
  const int tid = threadIdx.x;
  const int lane = tid & 63;
  const int wid = tid >> 6;
  const int wy = wid >> 1, wx = wid & 1;
  constexpr int WM = BM / 2, WN = BN / 2;
  constexpr int MB = WM / 16, NB = WN / 16;
  const int bm = blockIdx.x * BM;
  const int bn = blockIdx.y * BN;
  const int rlo = lane & 15, quad = lane >> 4;

  f32x4 acc[MB][NB] = {};

  for (int k0 = 0; k0 < K; k0 += 64) {
    for (int c = tid; c < BM * 8; c += 256) {
      int r = c >> 3, o = (c & 7) ^ (r & 7);
      __builtin_amdgcn_global_load_lds(
          (const __attribute__((address_space(1))) void*)(A + (size_t)(bm + r) * K + k0 + o * 8),
          (__attribute__((address_space(3))) void*)(As + c * 8), 16, 0, 0);
    }
    for (int c = tid; c < BN * 8; c += 256) {
      int r = c >> 3, o = (c & 7) ^ (r & 7);
      __builtin_amdgcn_global_load_lds(
          (const __attribute__((address_space(1))) void*)(W + (size_t)(bn + r) * K + k0 + o * 8),
          (__attribute__((address_space(3))) void*)(Ws + c * 8), 16, 0, 0);
    }
    __syncthreads();
#pragma unroll
    for (int kk = 0; kk < 2; kk++) {
      bf16x8 af[MB], bfr[NB];
#pragma unroll
      for (int mb = 0; mb < MB; mb++) {
        int r = wy * WM + mb * 16 + rlo;
        int o = (kk * 4 + quad) ^ (r & 7);
        af[mb] = *(const bf16x8*)(As + (r * 8 + o) * 8);
      }
#pragma unroll
      for (int nb = 0; nb < NB; nb++) {
        int r = wx * WN + nb * 16 + rlo;
        int o = (kk * 4 + quad) ^ (r & 7);
        bfr[nb] = *(const bf16x8*)(Ws + (r * 8 + o) * 8);
      }
#pragma unroll
      for (int mb = 0; mb < MB; mb++)
#pragma unroll
        for (int nb = 0; nb < NB; nb++)
          acc[mb][nb] = __builtin_amdgcn_mfma_f32_16x16x32_bf16(
              af[mb], bfr[nb], acc[mb][nb], 0, 0, 0);
    }
    __syncthreads();
  }

#pragma unroll
  for (int mb = 0; mb < MB; mb++) {
#pragma unroll
    for (int nb = 0; nb < NB; nb++) {
      int n = bn + wx * WN + nb * 16 + rlo;
      float bv = bias[n];
#pragma unroll
      for (int rg = 0; rg < 4; rg++) {
        int m = bm + wy * WM + mb * 16 + quad * 4 + rg;
        float val = tanhf(acc[mb][nb][rg] + bv);
        if constexpr (OUT_BF16) {
          Cb[(size_t)m * N + n] = __float2bfloat16(val);
        } else {
          Cf[(size_t)m * N + n] = val;
        }
      }
    }
  }
}

// ---------------- gemm2a: F = tanh(hb @ W2b^T + b2) + fused Anderson -------
// BM=32 rows/block (XCD-aligned remap), BN=256 (full N) -> block owns whole
// F rows; fresh F passes to the Anderson phase through LDS.
// mode 0: warm (F->slot fslot, X1=F, zc=bf16(F)); 1: anderson(tpos) -> X slot
// tpos%7 + zc; 2: anderson(tpos) -> out (f32), no zc.
__global__ __launch_bounds__(256) void gemm2a_kernel(
    const __hip_bfloat16* __restrict__ hb, const __hip_bfloat16* __restrict__ W2b,
    const float* __restrict__ b2, float* __restrict__ Xh, float* __restrict__ Fh,
    __hip_bfloat16* __restrict__ zc, float* __restrict__ out,
    int fslot, int tpos, int mode) {
  __shared__ __align__(16) u16 lds[(32 + 256) * 64];  // 36 KB staging
  __shared__ float Fl[32][260];                        // fresh F tile (pad 260)
  u16* As = lds;
  u16* Ws = lds + 32 * 64;
  const int tid = threadIdx.x;
  const int lane = tid & 63;
  const int wid = tid >> 6;
  const int wy = wid >> 1, wx = wid & 1;  // WM=16, WN=128
  const int rlo = lane & 15, quad = lane >> 4;
  const int b = blockIdx.x;
  const int rowbase = (b & 31) * 64 + (b >> 5) * 32;  // XCD-aligned rows

  f32x4 acc[8] = {};

  for (int k0 = 0; k0 < D_HID; k0 += 64) {
    for (int c = tid; c < 32 * 8; c += 256) {
      int r = c >> 3, o = (c & 7) ^ (r & 7);
      __builtin_amdgcn_global_load_lds(
          (const __attribute__((address_space(1))) void*)(hb + (size_t)(rowbase + r) * D_HID + k0 + o * 8),
          (__attribute__((address_space(3))) void*)(As + c * 8), 16, 0, 0);
    }
    for (int c = tid; c < 256 * 8; c += 256) {
      int r = c >> 3, o = (c & 7) ^ (r & 7);
      __builtin_amdgcn_global_load_lds(
          (const __attribute__((address_space(1))) void*)(W2b + (size_t)r * D_HID + k0 + o * 8),
          (__attribute__((address_space(3))) void*)(Ws + c * 8), 16, 0, 0);
    }
    __syncthreads();
#pragma unroll
    for (int kk = 0; kk < 2; kk++) {
      bf16x8 af;
      {
        int r = wy * 16 + rlo;
        int o = (kk * 4 + quad) ^ (r & 7);
        af = *(const bf16x8*)(As + (r * 8 + o) * 8);
      }
#pragma unroll
      for (int nb = 0; nb < 8; nb++) {
        int r = wx * 128 + nb * 16 + rlo;
        int o = (kk * 4 + quad) ^ (r & 7);
        bf16x8 bfr = *(const bf16x8*)(Ws + (r * 8 + o) * 8);
        acc[nb] = __builtin_amdgcn_mfma_f32_16x16x32_bf16(af, bfr, acc[nb], 0, 0, 0);
      }
    }
    __syncthreads();
  }

  // epilogue: write fresh F to LDS + global slot; warm mode also X1 + zc.
#pragma unroll
  for (int nb = 0; nb < 8; nb++) {
    int n = wx * 128 + nb * 16 + rlo;
    float bv = b2[n];
#pragma unroll
    for (int rg = 0; rg < 4; rg++) {
      int m = wy * 16 + quad * 4 + rg;           // local row
      int grow = rowbase + m;
      float val = tanhf(acc[nb][rg] + bv);
      Fl[m][n] = val;
      Fh[(size_t)fslot * SLOT + (size_t)grow * D_LAT + n] = val;
      if (mode == 0) {
        Xh[(size_t)SLOT + (size_t)grow * D_LAT + n] = val;
        zc[(size_t)grow * KCAT + n] = __float2bfloat16(val);
      }
    }
  }
  if (mode == 0) return;
  __syncthreads();

  // Anderson(tpos) for this block's 32 rows; wave handles 8 rows.
  const int mk = (tpos - 1 < 5) ? (tpos - 1) : 5;
  for (int rr = 0; rr < 8; rr++) {
    const int lr = wid * 8 + rr;
    const int grow = rowbase + lr;
    const size_t base = (size_t)grow * D_LAT + lane;

    float fa[4], xa[4], r[4], Fm1[4];
    {
      int sx = rdslot(tpos - 1);
#pragma unroll
      for (int c = 0; c < 4; c++) {
        fa[c] = Fl[lr][lane + 64 * c];            // fresh F[tpos-1]
        xa[c] = Xh[(size_t)sx * SLOT + base + 64 * c];
        r[c] = fa[c] - xa[c];
        Fm1[c] = fa[c];
      }
    }

    float dF[5][4], dG[5][4];
    for (int i = 1; i <= mk; i++) {
      int p = tpos - 1 - i;
      int s = rdslot(p);
#pragma unroll
      for (int c = 0; c < 4; c++) {
        float fb = (s == fslot) ? Fl[lr][lane + 64 * c]
                                : Fh[(size_t)s * SLOT + base + 64 * c];
        float xb = Xh[(size_t)s * SLOT + base + 64 * c];
        dF[i - 1][c] = fa[c] - fb;
        float dx = xa[c] - xb;
        dG[i - 1][c] = dF[i - 1][c] - dx;
        fa[c] = fb;
        xa[c] = xb;
      }
    }

    float vals[20];
    int nv = 0;
    for (int i = 0; i < mk; i++)
      for (int j = i; j < mk; j++) {
        float s = 0.f;
#pragma unroll
        for (int c = 0; c < 4; c++) s += dG[i][c] * dG[j][c];
        vals[nv++] = s;
      }
    for (int i = 0; i < mk; i++) {
      float s = 0.f;
#pragma unroll
      for (int c = 0; c < 4; c++) s += dG[i][c] * r[c];
      vals[nv++] = s;
    }
    for (int off = 1; off <= 32; off <<= 1)
      for (int v = 0; v < nv; v++) vals[v] += __shfl_xor(vals[v], off, 64);

    double A[5][5], bv[5], alpha[5];
    int p = 0;
    for (int i = 0; i < mk; i++)
      for (int j = i; j < mk; j++) {
        A[i][j] = (double)vals[p];
        A[j][i] = (double)vals[p];
        p++;
      }
    for (int i = 0; i < mk; i++) A[i][i] += (double)1e-4f;
    for (int i = 0; i < mk; i++) bv[i] = (double)vals[p++];

    for (int c = 0; c < mk; c++) {
      double inv = 1.0 / A[c][c];
      for (int rw = c + 1; rw < mk; rw++) {
        double fct = A[rw][c] * inv;
        for (int cc = c; cc < mk; cc++) A[rw][cc] -= fct * A[c][cc];
        bv[rw] -= fct * bv[c];
      }
    }
    for (int i = mk - 1; i >= 0; i--) {
      double s = bv[i];
      for (int j = i + 1; j < mk; j++) s -= A[i][j] * alpha[j];
      alpha[i] = s / A[i][i];
    }

    if (mode == 1) {
      float* Xw = Xh + (size_t)(tpos % NRING) * SLOT;
#pragma unroll
      for (int c = 0; c < 4; c++) {
        float x = Fm1[c];
        for (int i = 0; i < mk; i++) x -= dF[i][c] * (float)alpha[i];
        Xw[base + 64 * c] = x;
        zc[(size_t)grow * KCAT + lane + 64 * c] = __float2bfloat16(x);
      }
    } else {
#pragma unroll
      for (int c = 0; c < 4; c++) {
        float x = Fm1[c];
        for (int i = 0; i < mk; i++) x -= dF[i][c] * (float)alpha[i];
        out[base + 64 * c] = x;
      }
    }
  }
}

// ---------------- host orchestration ---------------------------------------
extern "C" void kernel_launch(void* const* d_in, const int* in_sizes, int n_in,
                              void* d_out, int out_size, void* d_ws,
                              size_t ws_size, hipStream_t stream) {
  const float* ctx = (const float*)d_in[0];
  const float* W1 = (const float*)d_in[1];
  const float* b1 = (const float*)d_in[2];
  const float* W2 = (const float*)d_in[3];
  const float* b2 = (const float*)d_in[4];
  float* out = (float*)d_out;

  float* ws = (float*)d_ws;
  float* sig = ws;                        // 16
  float* G1p = ws + 16;                   // 512*512
  float* G2 = G1p + KCAT * KCAT;          // 256*256
  float* Xh = G2 + D_LAT * D_LAT;         // 7*SLOT
  float* Fh = Xh + NRING * SLOT;          // 7*SLOT
  __hip_bfloat16* W1b = (__hip_bfloat16*)(Fh + NRING * SLOT);  // 524288
  __hip_bfloat16* W2b = W1b + D_HID * KCAT;                    // 262144
  __hip_bfloat16* zc = W2b + D_LAT * D_HID;                    // 2048*512
  __hip_bfloat16* hb = zc + B_ROWS * KCAT;                     // 2048*1024
  // ~38.6 MB total

  // 1) init: zc=[0|bf16(ctx)], G zeroed, X slot0 = 0
  init_kernel<<<4096, 256, 0, stream>>>(ctx, zc, G1p, G2, Xh);
  // 2) Gram matrices
  gram_kernel<<<640, 256, 0, stream>>>(W1, W2, G1p, G2);
  // 3) whole damped power chain + sigma (one block)
  chain_kernel<<<1, 1024, 0, stream>>>(W1, G1p, G2, sig);
  // 4) fold sigma into bf16 weights
  wfold_kernel<<<3072, 256, 0, stream>>>(W1, W2, sig, W1b, W2b);

  // evalF0: F0 -> slot0, X1 = F0, zc = bf16(F0)   (warm mode)
  gemm_mfma<64, 128, true><<<dim3(32, 8), 256, 0, stream>>>(
      zc, W1b, KCAT, b1, nullptr, hb, D_HID);
  gemm2a_kernel<<<64, 256, 0, stream>>>(hb, W2b, b2, Xh, Fh, zc, out,
                                        /*fslot=*/0, /*tpos=*/0, /*mode=*/0);
  // evalF1: F1 -> slot1 (F2===F1, X2===X1 via slot-redirect) + anderson(3)
  gemm_mfma<64, 128, true><<<dim3(32, 8), 256, 0, stream>>>(
      zc, W1b, KCAT, b1, nullptr, hb, D_HID);
  gemm2a_kernel<<<64, 256, 0, stream>>>(hb, W2b, b2, Xh, Fh, zc, out,
                                        /*fslot=*/1, /*tpos=*/3, /*mode=*/1);
  // t = 3..24: eval f(X[t]) -> F[t], fused anderson(t+1) (final -> out)
  for (int t = 3; t <= 24; t++) {
    gemm_mfma<64, 128, true><<<dim3(32, 8), 256, 0, stream>>>(
        zc, W1b, KCAT, b1, nullptr, hb, D_HID);
    gemm2a_kernel<<<64, 256, 0, stream>>>(hb, W2b, b2, Xh, Fh, zc, out,
                                          /*fslot=*/t % NRING, /*tpos=*/t + 1,
                                          /*mode=*/(t == 24) ? 2 : 1);
  }
}

// Round 8
// 5486.748 us; speedup vs baseline: 1.1286x; 1.1286x over previous
//
#include <hip/hip_runtime.h>
#include <hip/hip_bf16.h>

// ---------------------------------------------------------------------------
// DEQ layer, MI355X round 7.
//  - Round-7 fusions REVERTED (chain_kernel 621us single-CU; gemm2a 25%-CU).
//  - NEW: megaloop_kernel. The DEQ iteration is fully ROW-PRIVATE (row-wise
//    MLP + per-row Anderson), so one block owning 32 rows end-to-end can run
//    ALL 24 iterations internally with only __syncthreads() — no grid
//    barrier, no L2 flush, no co-residency need. h stays in LDS (bf16,
//    64KB); weights re-stream from L2 each iteration. Replaces the 69-
//    dispatch Anderson loop + 6 warm-up nodes with ONE dispatch.
//  - GEMM tiles/K-order and Anderson math bit-identical to verified rounds;
//    spectral pipeline = round-5 verified kernels verbatim. 27 nodes total.
// ---------------------------------------------------------------------------

#define B_ROWS 2048
#define D_LAT  256
#define D_CTX  256
#define D_HID  1024
#define KCAT   512
#define SLOT   (B_ROWS * D_LAT)
#define NRING  7

#define AS1 __attribute__((address_space(1)))
#define AS3 __attribute__((address_space(3)))

typedef __bf16 bf16x8 __attribute__((ext_vector_type(8)));
typedef float f32x4 __attribute__((ext_vector_type(4)));
typedef unsigned short u16;

// phantom position 2 (X2===X1, F2===F1) redirects to slot 1 (verified r7).
__device__ __forceinline__ int rdslot(int p) { return (p == 2) ? 1 : (p % NRING); }

// ---------------- init: zc=[0|bf16(ctx)], G=0, Xslot0=0, vA=0, uA=1 --------
__global__ void init_kernel(const float* __restrict__ ctx,
                            __hip_bfloat16* __restrict__ zc,
                            float* __restrict__ G1p, float* __restrict__ G2,
                            float* __restrict__ Xh, float* __restrict__ vA,
                            float* __restrict__ uA) {
  int i = blockIdx.x * 256 + threadIdx.x;
  if (i < B_ROWS * KCAT) {
    int b = i >> 9, c = i & 511;
    float v = (c < 256) ? 0.0f : ctx[b * 256 + (c - 256)];
    zc[i] = __float2bfloat16(v);
  }
  if (i < 512 * 512) G1p[i] = 0.0f;
  if (i < 256 * 256) G2[i] = 0.0f;
  if (i < SLOT) Xh[i] = 0.0f;
  if (i < KCAT) vA[i] = 0.0f;
  if (i < D_LAT) uA[i] = 1.0f;
}

// ---------------- Gram build, split-K x8, atomic accumulate (verified) -----
__global__ __launch_bounds__(256) void gram_kernel(
    const float* __restrict__ W1, const float* __restrict__ W2,
    float* __restrict__ G1p, float* __restrict__ G2) {
  __shared__ float As[32][65];
  __shared__ float Bs[32][65];
  const int tid = threadIdx.x;
  const int tx = tid & 15, ty = tid >> 4;

  const float* X; float* G; int N, ti, tj, k0base; bool modeA;
  int b = blockIdx.x;
  if (b < 512) {
    modeA = true; X = W1; G = G1p; N = 512;
    int s = b >> 6, t = b & 63;
    ti = t >> 3; tj = t & 7; k0base = s * 128;
  } else {
    modeA = false; b -= 512; X = W2; G = G2; N = 256;
    int s = b >> 4, t = b & 15;
    ti = t >> 2; tj = t & 3; k0base = s * 128;
  }

  float acc[4][4] = {};
  for (int k0 = k0base; k0 < k0base + 128; k0 += 32) {
    if (modeA) {
      for (int idx = tid; idx < 2048; idx += 256) {
        int r = idx & 63, c = idx >> 6;
        As[c][r] = X[(size_t)(k0 + c) * 512 + ti * 64 + r];
        Bs[c][r] = X[(size_t)(k0 + c) * 512 + tj * 64 + r];
      }
    } else {
      for (int idx = tid; idx < 2048; idx += 256) {
        int c = idx & 31, r = idx >> 5;
        As[c][r] = X[(size_t)(ti * 64 + r) * 1024 + k0 + c];
        Bs[c][r] = X[(size_t)(tj * 64 + r) * 1024 + k0 + c];
      }
    }
    __syncthreads();
#pragma unroll
    for (int kk = 0; kk < 32; kk++) {
      float a[4], bb[4];
#pragma unroll
      for (int i = 0; i < 4; i++) a[i] = As[kk][ty * 4 + i];
#pragma unroll
      for (int j = 0; j < 4; j++) bb[j] = Bs[kk][tx * 4 + j];
#pragma unroll
      for (int i = 0; i < 4; i++)
#pragma unroll
        for (int j = 0; j < 4; j++) acc[i][j] += a[i] * bb[j];
    }
    __syncthreads();
  }
#pragma unroll
  for (int i = 0; i < 4; i++)
#pragma unroll
    for (int j = 0; j < 4; j++)
      atomicAdd(&G[(size_t)(ti * 64 + ty * 4 + i) * N + tj * 64 + tx * 4 + j],
                acc[i][j]);
}

// ---------------- colsum: vA += W1^T ones (verified round 5) ---------------
__global__ __launch_bounds__(256) void colsum_kernel(
    const float* __restrict__ W1, float* __restrict__ vA) {
  int b = blockIdx.x;
  for (int c = threadIdx.x; c < KCAT; c += 256) {
    float s = 0.f;
#pragma unroll
    for (int r = 0; r < 16; r++) s += W1[(size_t)(16 * b + r) * KCAT + c];
    atomicAdd(&vA[c], s);
  }
}

// ---------------- joint power matvec (verified round 5) --------------------
__global__ __launch_bounds__(256) void pmv_kernel(
    const float* __restrict__ G1p, const float* __restrict__ G2,
    const float* __restrict__ vi, float* __restrict__ vo,
    const float* __restrict__ ui, float* __restrict__ uo, int g1_active) {
  int gw = blockIdx.x * 4 + (threadIdx.x >> 6);
  int lane = threadIdx.x & 63;
  const float* G; const float* in; float* out; int n, r;
  if (gw < 512) {
    if (!g1_active) return;
    G = G1p; in = vi; out = vo; n = 512; r = gw;
  } else {
    G = G2; in = ui; out = uo; n = 256; r = gw - 512;
  }
  const float4* Gr = (const float4*)(G + (size_t)r * n);
  const float4* uv = (const float4*)in;
  float acc = 0.f;
  for (int c = lane; c < (n >> 2); c += 64) {
    float4 g = Gr[c], u = uv[c];
    acc += g.x * u.x + g.y * u.y + g.z * u.z + g.w * u.w;
  }
  for (int off = 32; off; off >>= 1) acc += __shfl_down(acc, off, 64);
  if (lane == 0) out[r] = 0.25f * acc;
}

// ---------------- sigma (verified round 5) ---------------------------------
__global__ __launch_bounds__(256) void sigma_kernel(
    const float* __restrict__ vA, const float* __restrict__ vB,
    const float* __restrict__ uA, const float* __restrict__ uB,
    float* __restrict__ sig) {
  float s[4] = {0.f, 0.f, 0.f, 0.f};
  for (int i = threadIdx.x; i < KCAT; i += 256) {
    s[0] += vA[i] * vB[i];
    s[1] += vA[i] * vA[i];
  }
  for (int i = threadIdx.x; i < D_LAT; i += 256) {
    s[2] += uA[i] * uA[i];
    s[3] += uA[i] * uB[i];
  }
  __shared__ float red[4][4];
  int lane = threadIdx.x & 63, w = threadIdx.x >> 6;
  for (int k = 0; k < 4; k++) {
    float a = s[k];
    for (int off = 32; off; off >>= 1) a += __shfl_down(a, off, 64);
    if (lane == 0) red[k][w] = a;
  }
  __syncthreads();
  if (threadIdx.x == 0) {
    float d0 = red[0][0] + red[0][1] + red[0][2] + red[0][3];
    float d1 = red[1][0] + red[1][1] + red[1][2] + red[1][3];
    float d2 = red[2][0] + red[2][1] + red[2][2] + red[2][3];
    float d3 = red[3][0] + red[3][1] + red[3][2] + red[3][3];
    sig[0] = sqrtf(0.25f * d0 / d1);
    sig[1] = sqrtf(0.25f * d2 / d3);
  }
}

// ---------------- fold sigma into bf16 weights (verified) ------------------
__global__ void wfold_kernel(const float* __restrict__ W1,
                             const float* __restrict__ W2,
                             const float* __restrict__ sig,
                             __hip_bfloat16* __restrict__ W1b,
                             __hip_bfloat16* __restrict__ W2b) {
  int i = blockIdx.x * 256 + threadIdx.x;
  if (i < D_HID * KCAT) W1b[i] = __float2bfloat16(W1[i] * sig[0]);
  int j = i - D_HID * KCAT;
  if (j >= 0 && j < D_LAT * D_HID) W2b[j] = __float2bfloat16(W2[j] * sig[1]);
}

// ---------------- THE megaloop: 24 DEQ iterations, one dispatch ------------
// 64 blocks x 256 thr; block owns rows [32b, 32b+32) end-to-end. No
// cross-block data flow: __syncthreads (drains vmcnt) is sufficient sync.
__global__ __launch_bounds__(256) void megaloop_kernel(
    const __hip_bfloat16* __restrict__ W1b,
    const __hip_bfloat16* __restrict__ W2b, const float* __restrict__ b1,
    const float* __restrict__ b2, float* __restrict__ Xh,
    float* __restrict__ Fh, __hip_bfloat16* __restrict__ zc,
    float* __restrict__ out) {
  // hbuf: bf16 h tile [32][1024], octet-XOR swizzled per row (64 KB).
  __shared__ __align__(16) u16 hbuf[32 * 1024];
  // staging union: stage (32 KB, W1b/W2b tiles) + stageA (4 KB, zc tile);
  // Fl (fresh F, 32x260 f32 = 33.3 KB) aliases it after phase-2 k-loop.
  __shared__ __align__(16) unsigned char smem[36864];
  u16* stage = (u16*)smem;
  u16* stageA = (u16*)(smem + 32768);
  float(*Fl)[260] = (float(*)[260])smem;

  const int tid = threadIdx.x;
  const int lane = tid & 63;
  const int wid = tid >> 6;
  const int wy = wid >> 1, wx = wid & 1;
  const int rlo = lane & 15, quad = lane >> 4;
  const int rowbase = blockIdx.x * 32;

  for (int step = 0; step < 24; step++) {
    int mode, fslot, tpos;
    if (step == 0) { mode = 0; fslot = 0; tpos = 0; }
    else if (step == 1) { mode = 1; fslot = 1; tpos = 3; }
    else {
      int t = step + 1;                    // F position t = 3..24
      fslot = t % NRING; tpos = t + 1; mode = (t == 24) ? 2 : 1;
    }

    // ---- phase 1: hbuf = bf16(tanh(zc[rows] @ W1b^T + b1)), N=1024 -------
    for (int nch = 0; nch < 8; nch++) {
      f32x4 acc[4] = {};
      for (int k0 = 0; k0 < KCAT; k0 += 64) {
        {  // zc tile 32x64: 256 chunks, one pass
          int c = tid;
          int r = c >> 3, o = (c & 7) ^ (r & 7);
          __builtin_amdgcn_global_load_lds(
              (const AS1 void*)(zc + (size_t)(rowbase + r) * KCAT + k0 + o * 8),
              (AS3 void*)(stageA + c * 8), 16, 0, 0);
        }
        for (int c = tid; c < 128 * 8; c += 256) {  // W1b tile 128x64
          int r = c >> 3, o = (c & 7) ^ (r & 7);
          __builtin_amdgcn_global_load_lds(
              (const AS1 void*)(W1b + (size_t)(nch * 128 + r) * KCAT + k0 + o * 8),
              (AS3 void*)(stage + c * 8), 16, 0, 0);
        }
        __syncthreads();
#pragma unroll
        for (int kk = 0; kk < 2; kk++) {
          bf16x8 af;
          {
            int r = wy * 16 + rlo;
            int o = (kk * 4 + quad) ^ (r & 7);
            af = *(const bf16x8*)(stageA + (r * 8 + o) * 8);
          }
#pragma unroll
          for (int nb = 0; nb < 4; nb++) {
            int r = wx * 64 + nb * 16 + rlo;
            int o = (kk * 4 + quad) ^ (r & 7);
            bf16x8 bfr = *(const bf16x8*)(stage + (r * 8 + o) * 8);
            acc[nb] = __builtin_amdgcn_mfma_f32_16x16x32_bf16(af, bfr, acc[nb],
                                                              0, 0, 0);
          }
        }
        __syncthreads();
      }
      // epilogue -> hbuf (octet-XOR layout; regions exclusive per wave)
#pragma unroll
      for (int nb = 0; nb < 4; nb++) {
        int n = nch * 128 + wx * 64 + nb * 16 + rlo;
        float bv = b1[n];
#pragma unroll
        for (int rg = 0; rg < 4; rg++) {
          int m = wy * 16 + quad * 4 + rg;
          float val = tanhf(acc[nb][rg] + bv);
          __hip_bfloat16 hv = __float2bfloat16(val);
          int oct = n >> 3, j = n & 7;
          hbuf[m * 1024 + (((oct & ~7) | ((oct & 7) ^ (m & 7))) << 3) + j] =
              *(const u16*)&hv;
        }
      }
    }
    __syncthreads();

    // ---- phase 2: F = tanh(h @ W2b^T + b2), A from LDS hbuf --------------
    f32x4 acc2[8] = {};
    for (int k0 = 0; k0 < D_HID; k0 += 64) {
      for (int c = tid; c < 256 * 8; c += 256) {  // W2b tile 256x64
        int r = c >> 3, o = (c & 7) ^ (r & 7);
        __builtin_amdgcn_global_load_lds(
            (const AS1 void*)(W2b + (size_t)r * D_HID + k0 + o * 8),
            (AS3 void*)(stage + c * 8), 16, 0, 0);
      }
      __syncthreads();
#pragma unroll
      for (int kk = 0; kk < 2; kk++) {
        bf16x8 af;
        {
          int r = wy * 16 + rlo;
          af = *(const bf16x8*)(hbuf + r * 1024 + k0 +
                                (((kk * 4 + quad) ^ (r & 7)) << 3));
        }
#pragma unroll
        for (int nb = 0; nb < 8; nb++) {
          int r = wx * 128 + nb * 16 + rlo;
          int o = (kk * 4 + quad) ^ (r & 7);
          bf16x8 bfr = *(const bf16x8*)(stage + (r * 8 + o) * 8);
          acc2[nb] = __builtin_amdgcn_mfma_f32_16x16x32_bf16(af, bfr, acc2[nb],
                                                             0, 0, 0);
        }
      }
      __syncthreads();  // also makes stage safe to alias as Fl after loop
    }

    // ---- epilogue: Fl (LDS) + Fh slot (+X1/zc in warm mode 0) ------------
#pragma unroll
    for (int nb = 0; nb < 8; nb++) {
      int n = wx * 128 + nb * 16 + rlo;
      float bv = b2[n];
#pragma unroll
      for (int rg = 0; rg < 4; rg++) {
        int m = wy * 16 + quad * 4 + rg;
        int grow = rowbase + m;
        float val = tanhf(acc2[nb][rg] + bv);
        Fl[m][n] = val;
        Fh[(size_t)fslot * SLOT + (size_t)grow * D_LAT + n] = val;
        if (mode == 0) {
          Xh[(size_t)SLOT + (size_t)grow * D_LAT + n] = val;
          zc[(size_t)grow * KCAT + n] = __float2bfloat16(val);
        }
      }
    }
    __syncthreads();

    // ---- phase 3: Anderson(tpos) for own 32 rows (verified r7 logic) -----
    if (mode != 0) {
      const int mk = (tpos - 1 < 5) ? (tpos - 1) : 5;
      for (int rr = 0; rr < 8; rr++) {
        const int lr = wid * 8 + rr;
        const int grow = rowbase + lr;
        const size_t base = (size_t)grow * D_LAT + lane;

        float fa[4], xa[4], r[4], Fm1[4];
        {
          int sx = rdslot(tpos - 1);
#pragma unroll
          for (int c = 0; c < 4; c++) {
            fa[c] = Fl[lr][lane + 64 * c];
            xa[c] = Xh[(size_t)sx * SLOT + base + 64 * c];
            r[c] = fa[c] - xa[c];
            Fm1[c] = fa[c];
          }
        }

        float dF[5][4], dG[5][4];
        for (int i = 1; i <= mk; i++) {
          int p = tpos - 1 - i;
          int s = rdslot(p);
#pragma unroll
          for (int c = 0; c < 4; c++) {
            float fb = (s == fslot) ? Fl[lr][lane + 64 * c]
                                    : Fh[(size_t)s * SLOT + base + 64 * c];
            float xb = Xh[(size_t)s * SLOT + base + 64 * c];
            dF[i - 1][c] = fa[c] - fb;
            float dx = xa[c] - xb;
            dG[i - 1][c] = dF[i - 1][c] - dx;
            fa[c] = fb;
            xa[c] = xb;
          }
        }

        float vals[20];
        int nv = 0;
        for (int i = 0; i < mk; i++)
          for (int j = i; j < mk; j++) {
            float s = 0.f;
#pragma unroll
            for (int c = 0; c < 4; c++) s += dG[i][c] * dG[j][c];
            vals[nv++] = s;
          }
        for (int i = 0; i < mk; i++) {
          float s = 0.f;
#pragma unroll
          for (int c = 0; c < 4; c++) s += dG[i][c] * r[c];
          vals[nv++] = s;
        }
        for (int off = 1; off <= 32; off <<= 1)
          for (int v = 0; v < nv; v++) vals[v] += __shfl_xor(vals[v], off, 64);

        double A[5][5], bv[5], alpha[5];
        int p = 0;
        for (int i = 0; i < mk; i++)
          for (int j = i; j < mk; j++) {
            A[i][j] = (double)vals[p];
            A[j][i] = (double)vals[p];
            p++;
          }
        for (int i = 0; i < mk; i++) A[i][i] += (double)1e-4f;
        for (int i = 0; i < mk; i++) bv[i] = (double)vals[p++];

        for (int c = 0; c < mk; c++) {
          double inv = 1.0 / A[c][c];
          for (int rw = c + 1; rw < mk; rw++) {
            double fct = A[rw][c] * inv;
            for (int cc = c; cc < mk; cc++) A[rw][cc] -= fct * A[c][cc];
            bv[rw] -= fct * bv[c];
          }
        }
        for (int i = mk - 1; i >= 0; i--) {
          double s = bv[i];
          for (int j = i + 1; j < mk; j++) s -= A[i][j] * alpha[j];
          alpha[i] = s / A[i][i];
        }

        if (mode == 1) {
          float* Xw = Xh + (size_t)(tpos % NRING) * SLOT;
#pragma unroll
          for (int c = 0; c < 4; c++) {
            float x = Fm1[c];
            for (int i = 0; i < mk; i++) x -= dF[i][c] * (float)alpha[i];
            Xw[base + 64 * c] = x;
            zc[(size_t)grow * KCAT + lane + 64 * c] = __float2bfloat16(x);
          }
        } else {
#pragma unroll
          for (int c = 0; c < 4; c++) {
            float x = Fm1[c];
            for (int i = 0; i < mk; i++) x -= dF[i][c] * (float)alpha[i];
            out[base + 64 * c] = x;
          }
        }
      }
    }
    __syncthreads();  // zc/Fl/stage safe for next step
  }
}

// ---------------- host orchestration ---------------------------------------
extern "C" void kernel_launch(void* const* d_in, const int* in_sizes, int n_in,
                              void* d_out, int out_size, void* d_ws,
                              size_t ws_size, hipStream_t stream) {
  const float* ctx = (const float*)d_in[0];
  const float* W1 = (const float*)d_in[1];
  const float* b1 = (const float*)d_in[2];
  const float* W2 = (const float*)d_in[3];
  const float* b2 = (const float*)d_in[4];
  float* out = (float*)d_out;

  float* ws = (float*)d_ws;
  float* sig = ws;                        // 16
  float* vA = ws + 16;                    // 512
  float* vB = vA + KCAT;                  // 512
  float* uA = vB + KCAT;                  // 256
  float* uB = uA + D_LAT;                 // 256
  float* G1p = uB + D_LAT;                // 512*512
  float* G2 = G1p + KCAT * KCAT;          // 256*256
  float* Xh = G2 + D_LAT * D_LAT;         // 7*SLOT
  float* Fh = Xh + NRING * SLOT;          // 7*SLOT
  __hip_bfloat16* W1b = (__hip_bfloat16*)(Fh + NRING * SLOT);  // 524288
  __hip_bfloat16* W2b = W1b + D_HID * KCAT;                    // 262144
  __hip_bfloat16* zc = W2b + D_LAT * D_HID;                    // 2048*512
  // ~34.3 MB total (hb eliminated — h lives in LDS)

  // spectral pipeline (round-5 verified, 26 nodes)
  init_kernel<<<4096, 256, 0, stream>>>(ctx, zc, G1p, G2, Xh, vA, uA);
  gram_kernel<<<640, 256, 0, stream>>>(W1, W2, G1p, G2);
  colsum_kernel<<<64, 256, 0, stream>>>(W1, vA);
  for (int it = 1; it <= 21; it++) {
    const float* vi; float* vo;
    const float* ui; float* uo;
    if (it & 1) { vi = vB; vo = vA; ui = uA; uo = uB; }
    else        { vi = vA; vo = vB; ui = uB; uo = uA; }
    pmv_kernel<<<192, 256, 0, stream>>>(G1p, G2, vi, vo, ui, uo, it >= 2);
  }
  sigma_kernel<<<1, 256, 0, stream>>>(vA, vB, uA, uB, sig);
  wfold_kernel<<<3072, 256, 0, stream>>>(W1, W2, sig, W1b, W2b);

  // the whole DEQ loop: warm-up + 23 Anderson iterations, ONE dispatch
  megaloop_kernel<<<64, 256, 0, stream>>>(W1b, W2b, b1, b2, Xh, Fh, zc, out);
}

// Round 9
// 1752.158 us; speedup vs baseline: 3.5340x; 3.1314x over previous
//
#include <hip/hip_runtime.h>
#include <hip/hip_bf16.h>

// ---------------------------------------------------------------------------
// DEQ layer, MI355X round 8.
//  - r7/r8 full-fusion attempts REVERTED (row-private fusion forces per-block
//    re-read of all weights; XCD-L2 thrash measured: FETCH 354 MB, 2.8us/
//    staging round). Back to round-5 measured-best multi-kernel structure.
//  - Lever 1: spectral chain via operator squaring. Ghat = G/8, M = Ghat^4
//    (two 80-block f32 GEMM squarings); v: Ghat^3 -> M^4 -> Ghat (8 joint
//    matvec launches, u-chain M^5 -> Ghat rides along). sigma with damp-1/8
//    compensation (0.125 factor). Spectral nodes 26 -> 14.
//  - Lever 2: BK=128 GEMM K-loop (half the staging rounds; same MFMA K-order
//    -> bitwise-identical outputs). LDS 48/32 KB.
// ---------------------------------------------------------------------------

#define B_ROWS 2048
#define D_LAT  256
#define D_CTX  256
#define D_HID  1024
#define KCAT   512
#define SLOT   (B_ROWS * D_LAT)
#define NRING  7

#define AS1 __attribute__((address_space(1)))
#define AS3 __attribute__((address_space(3)))

typedef __bf16 bf16x8 __attribute__((ext_vector_type(8)));
typedef float f32x4 __attribute__((ext_vector_type(4)));
typedef unsigned short u16;

// ---------------- init: zc=[0|bf16(ctx)], G=0, Xslot0=0, vA=0, uA=1 --------
__global__ void init_kernel(const float* __restrict__ ctx,
                            __hip_bfloat16* __restrict__ zc,
                            float* __restrict__ G1p, float* __restrict__ G2,
                            float* __restrict__ Xh, float* __restrict__ vA,
                            float* __restrict__ uA) {
  int i = blockIdx.x * 256 + threadIdx.x;
  if (i < B_ROWS * KCAT) {
    int b = i >> 9, c = i & 511;
    float v = (c < 256) ? 0.0f : ctx[b * 256 + (c - 256)];
    zc[i] = __float2bfloat16(v);
  }
  if (i < 512 * 512) G1p[i] = 0.0f;
  if (i < 256 * 256) G2[i] = 0.0f;
  if (i < SLOT) Xh[i] = 0.0f;
  if (i < KCAT) vA[i] = 0.0f;
  if (i < D_LAT) uA[i] = 1.0f;
}

// ---------------- Gram build, split-K x8, atomic accumulate (verified) -----
__global__ __launch_bounds__(256) void gram_kernel(
    const float* __restrict__ W1, const float* __restrict__ W2,
    float* __restrict__ G1p, float* __restrict__ G2) {
  __shared__ float As[32][65];
  __shared__ float Bs[32][65];
  const int tid = threadIdx.x;
  const int tx = tid & 15, ty = tid >> 4;

  const float* X; float* G; int N, ti, tj, k0base; bool modeA;
  int b = blockIdx.x;
  if (b < 512) {
    modeA = true; X = W1; G = G1p; N = 512;
    int s = b >> 6, t = b & 63;
    ti = t >> 3; tj = t & 7; k0base = s * 128;
  } else {
    modeA = false; b -= 512; X = W2; G = G2; N = 256;
    int s = b >> 4, t = b & 15;
    ti = t >> 2; tj = t & 3; k0base = s * 128;
  }

  float acc[4][4] = {};
  for (int k0 = k0base; k0 < k0base + 128; k0 += 32) {
    if (modeA) {
      for (int idx = tid; idx < 2048; idx += 256) {
        int r = idx & 63, c = idx >> 6;
        As[c][r] = X[(size_t)(k0 + c) * 512 + ti * 64 + r];
        Bs[c][r] = X[(size_t)(k0 + c) * 512 + tj * 64 + r];
      }
    } else {
      for (int idx = tid; idx < 2048; idx += 256) {
        int c = idx & 31, r = idx >> 5;
        As[c][r] = X[(size_t)(ti * 64 + r) * 1024 + k0 + c];
        Bs[c][r] = X[(size_t)(tj * 64 + r) * 1024 + k0 + c];
      }
    }
    __syncthreads();
#pragma unroll
    for (int kk = 0; kk < 32; kk++) {
      float a[4], bb[4];
#pragma unroll
      for (int i = 0; i < 4; i++) a[i] = As[kk][ty * 4 + i];
#pragma unroll
      for (int j = 0; j < 4; j++) bb[j] = Bs[kk][tx * 4 + j];
#pragma unroll
      for (int i = 0; i < 4; i++)
#pragma unroll
        for (int j = 0; j < 4; j++) acc[i][j] += a[i] * bb[j];
    }
    __syncthreads();
  }
#pragma unroll
  for (int i = 0; i < 4; i++)
#pragma unroll
    for (int j = 0; j < 4; j++)
      atomicAdd(&G[(size_t)(ti * 64 + ty * 4 + i) * N + tj * 64 + tx * 4 + j],
                acc[i][j]);
}

// ---------------- colsum: vA += W1^T ones (verified round 5) ---------------
__global__ __launch_bounds__(256) void colsum_kernel(
    const float* __restrict__ W1, float* __restrict__ vA) {
  int b = blockIdx.x;
  for (int c = threadIdx.x; c < KCAT; c += 256) {
    float s = 0.f;
#pragma unroll
    for (int r = 0; r < 16; r++) s += W1[(size_t)(16 * b + r) * KCAT + c];
    atomicAdd(&vA[c], s);
  }
}

// ---------------- squaring: out = scale * in . in^T (symmetric in) ---------
// blocks 0..63: 512-matrix (8x8 tiles of 64); 64..79: 256-matrix (4x4).
__global__ __launch_bounds__(256) void sq_kernel(
    const float* __restrict__ in1, float* __restrict__ out1,
    const float* __restrict__ in2, float* __restrict__ out2, float scale) {
  __shared__ float As[32][65];
  __shared__ float Bs[32][65];
  const int tid = threadIdx.x;
  const int tx = tid & 15, ty = tid >> 4;

  const float* X; float* S; int N, ti, tj;
  int b = blockIdx.x;
  if (b < 64) { X = in1; S = out1; N = 512; ti = b >> 3; tj = b & 7; }
  else { b -= 64; X = in2; S = out2; N = 256; ti = b >> 2; tj = b & 3; }

  float acc[4][4] = {};
  for (int k0 = 0; k0 < N; k0 += 32) {
    for (int idx = tid; idx < 2048; idx += 256) {
      int c = idx & 31, r = idx >> 5;
      As[c][r] = X[(size_t)(ti * 64 + r) * N + k0 + c];
      Bs[c][r] = X[(size_t)(tj * 64 + r) * N + k0 + c];
    }
    __syncthreads();
#pragma unroll
    for (int kk = 0; kk < 32; kk++) {
      float a[4], bb[4];
#pragma unroll
      for (int i = 0; i < 4; i++) a[i] = As[kk][ty * 4 + i];
#pragma unroll
      for (int j = 0; j < 4; j++) bb[j] = Bs[kk][tx * 4 + j];
#pragma unroll
      for (int i = 0; i < 4; i++)
#pragma unroll
        for (int j = 0; j < 4; j++) acc[i][j] += a[i] * bb[j];
    }
    __syncthreads();
  }
#pragma unroll
  for (int i = 0; i < 4; i++)
#pragma unroll
    for (int j = 0; j < 4; j++)
      S[(size_t)(ti * 64 + ty * 4 + i) * N + tj * 64 + tx * 4 + j] =
          scale * acc[i][j];
}

// ---------------- joint matvec: xo = s * (P x) for v(512) and u(256) -------
__global__ __launch_bounds__(256) void mv_kernel(
    const float* __restrict__ Pv, const float* __restrict__ xvi,
    float* __restrict__ xvo, float sv, const float* __restrict__ Pu,
    const float* __restrict__ xui, float* __restrict__ xuo, float su,
    int u_active) {
  int gw = blockIdx.x * 4 + (threadIdx.x >> 6);
  int lane = threadIdx.x & 63;
  const float* P; const float* xin; float* xout; float s; int n, r;
  if (gw < 512) {
    P = Pv; xin = xvi; xout = xvo; s = sv; n = 512; r = gw;
  } else {
    if (!u_active) return;
    P = Pu; xin = xui; xout = xuo; s = su; n = 256; r = gw - 512;
  }
  const float4* Pr = (const float4*)(P + (size_t)r * n);
  const float4* xv = (const float4*)xin;
  float acc = 0.f;
  for (int c = lane; c < (n >> 2); c += 64) {
    float4 g = Pr[c], u = xv[c];
    acc += g.x * u.x + g.y * u.y + g.z * u.z + g.w * u.w;
  }
  for (int off = 32; off; off >>= 1) acc += __shfl_down(acc, off, 64);
  if (lane == 0) xout[r] = s * acc;
}

// ---------------- sigma (damp = 1/8): args (v20, v19, u20, u21) ------------
__global__ __launch_bounds__(256) void sigma_kernel(
    const float* __restrict__ v20, const float* __restrict__ v19,
    const float* __restrict__ u20, const float* __restrict__ u21,
    float* __restrict__ sig) {
  float s[4] = {0.f, 0.f, 0.f, 0.f};
  for (int i = threadIdx.x; i < KCAT; i += 256) {
    s[0] += v20[i] * v19[i];
    s[1] += v20[i] * v20[i];
  }
  for (int i = threadIdx.x; i < D_LAT; i += 256) {
    s[2] += u20[i] * u20[i];
    s[3] += u20[i] * u21[i];
  }
  __shared__ float red[4][4];
  int lane = threadIdx.x & 63, w = threadIdx.x >> 6;
  for (int k = 0; k < 4; k++) {
    float a = s[k];
    for (int off = 32; off; off >>= 1) a += __shfl_down(a, off, 64);
    if (lane == 0) red[k][w] = a;
  }
  __syncthreads();
  if (threadIdx.x == 0) {
    float d0 = red[0][0] + red[0][1] + red[0][2] + red[0][3];
    float d1 = red[1][0] + red[1][1] + red[1][2] + red[1][3];
    float d2 = red[2][0] + red[2][1] + red[2][2] + red[2][3];
    float d3 = red[3][0] + red[3][1] + red[3][2] + red[3][3];
    sig[0] = sqrtf(0.125f * d0 / d1);   // 1/sigma1
    sig[1] = sqrtf(0.125f * d2 / d3);   // 1/sigma2
  }
}

// ---------------- fold sigma into bf16 weights (verified) ------------------
__global__ void wfold_kernel(const float* __restrict__ W1,
                             const float* __restrict__ W2,
                             const float* __restrict__ sig,
                             __hip_bfloat16* __restrict__ W1b,
                             __hip_bfloat16* __restrict__ W2b) {
  int i = blockIdx.x * 256 + threadIdx.x;
  if (i < D_HID * KCAT) W1b[i] = __float2bfloat16(W1[i] * sig[0]);
  int j = i - D_HID * KCAT;
  if (j >= 0 && j < D_LAT * D_HID) W2b[j] = __float2bfloat16(W2[j] * sig[1]);
}

// ---------------- warm-up fusions (verified round 4/5) ---------------------
__global__ void warm1_kernel(const float* __restrict__ Fh,
                             float* __restrict__ Xh,
                             __hip_bfloat16* __restrict__ zc) {
  int i = blockIdx.x * 256 + threadIdx.x;
  float v = Fh[i];
  Xh[SLOT + i] = v;
  zc[(i >> 8) * KCAT + (i & 255)] = __float2bfloat16(v);
}
__global__ void warm2_kernel(const float* __restrict__ Fh,
                             float* __restrict__ Xh, float* __restrict__ Fw) {
  int i = blockIdx.x * 256 + threadIdx.x;
  Xh[2 * SLOT + i] = Fh[i];
  Fw[2 * SLOT + i] = Fh[SLOT + i];
}

// ---------------- bf16 MFMA GEMM, BK=128: C = tanh(A @ W^T + bias) ---------
// Same MFMA K-order as the verified BK=64 version (bitwise-identical C).
// Staging keeps LDS dst linear-in-lane (wave-uniform base + lane*16B); the
// XOR-octet swizzle is applied on the global SRC side, 4-bit chunk index
// with XOR on the low 3 bits only.
template <int BM, int BN, bool OUT_BF16>
__global__ __launch_bounds__(256) void gemm_mfma(
    const __hip_bfloat16* __restrict__ A, const __hip_bfloat16* __restrict__ W,
    int K, const float* __restrict__ bias, float* __restrict__ Cf,
    __hip_bfloat16* __restrict__ Cb, int N) {
  __shared__ __align__(16) u16 lds[(BM + BN) * 128];
  u16* As = lds;
  u16* Ws = lds + BM * 128;
  const int tid = threadIdx.x;
  const int lane = tid & 63;
  const int wid = tid >> 6;
  const int wy = wid >> 1, wx = wid & 1;
  constexpr int WM = BM / 2, WN = BN / 2;
  constexpr int MB = WM / 16, NB = WN / 16;
  const int bm = blockIdx.x * BM;
  const int bn = blockIdx.y * BN;
  const int rlo = lane & 15, quad = lane >> 4;

  f32x4 acc[MB][NB] = {};

  for (int k0 = 0; k0 < K; k0 += 128) {
    for (int c = tid; c < BM * 16; c += 256) {
      int r = c >> 4, cc = c & 15;
      int o = (cc & 8) | ((cc & 7) ^ (r & 7));
      __builtin_amdgcn_global_load_lds(
          (const AS1 void*)(A + (size_t)(bm + r) * K + k0 + o * 8),
          (AS3 void*)(As + c * 8), 16, 0, 0);
    }
    for (int c = tid; c < BN * 16; c += 256) {
      int r = c >> 4, cc = c & 15;
      int o = (cc & 8) | ((cc & 7) ^ (r & 7));
      __builtin_amdgcn_global_load_lds(
          (const AS1 void*)(W + (size_t)(bn + r) * K + k0 + o * 8),
          (AS3 void*)(Ws + c * 8), 16, 0, 0);
    }
    __syncthreads();
#pragma unroll
    for (int kk = 0; kk < 4; kk++) {
      bf16x8 af[MB], bfr[NB];
#pragma unroll
      for (int mb = 0; mb < MB; mb++) {
        int r = wy * WM + mb * 16 + rlo;
        int idx = kk * 4 + quad;
        int o = (idx & 8) | ((idx & 7) ^ (r & 7));
        af[mb] = *(const bf16x8*)(As + (r * 16 + o) * 8);
      }
#pragma unroll
      for (int nb = 0; nb < NB; nb++) {
        int r = wx * WN + nb * 16 + rlo;
        int idx = kk * 4 + quad;
        int o = (idx & 8) | ((idx & 7) ^ (r & 7));
        bfr[nb] = *(const bf16x8*)(Ws + (r * 16 + o) * 8);
      }
#pragma unroll
      for (int mb = 0; mb < MB; mb++)
#pragma unroll
        for (int nb = 0; nb < NB; nb++)
          acc[mb][nb] = __builtin_amdgcn_mfma_f32_16x16x32_bf16(
              af[mb], bfr[nb], acc[mb][nb], 0, 0, 0);
    }
    __syncthreads();
  }

#pragma unroll
  for (int mb = 0; mb < MB; mb++) {
#pragma unroll
    for (int nb = 0; nb < NB; nb++) {
      int n = bn + wx * WN + nb * 16 + rlo;
      float bv = bias[n];
#pragma unroll
      for (int rg = 0; rg < 4; rg++) {
        int m = bm + wy * WM + mb * 16 + quad * 4 + rg;
        float val = tanhf(acc[mb][nb][rg] + bv);
        if constexpr (OUT_BF16) {
          Cb[(size_t)m * N + n] = __float2bfloat16(val);
        } else {
          Cf[(size_t)m * N + n] = val;
        }
      }
    }
  }
}

// ---------------- Anderson step (wave per batch row, verified) -------------
__global__ __launch_bounds__(256) void anderson_step_kernel(
    const float* __restrict__ Xh, const float* __restrict__ Fh,
    float* __restrict__ Xw, __hip_bfloat16* __restrict__ zc, int t, int mk) {
  const int lane = threadIdx.x & 63;
  const int wid = threadIdx.x >> 6;
  const int b = blockIdx.x * 4 + wid;
  const int base = b * D_LAT + lane;

  float fa[4], xa[4], r[4], Fm1[4];
#pragma unroll
  for (int c = 0; c < 4; c++) {
    int sl = (t - 1) % NRING;
    fa[c] = Fh[sl * SLOT + base + 64 * c];
    xa[c] = Xh[sl * SLOT + base + 64 * c];
    r[c] = fa[c] - xa[c];
    Fm1[c] = fa[c];
  }

  float dF[5][4], dG[5][4];
  for (int i = 1; i <= mk; i++) {
    int sl = (t - 1 - i) % NRING;
#pragma unroll
    for (int c = 0; c < 4; c++) {
      float fb = Fh[sl * SLOT + base + 64 * c];
      float xb = Xh[sl * SLOT + base + 64 * c];
      dF[i - 1][c] = fa[c] - fb;
      float dx = xa[c] - xb;
      dG[i - 1][c] = dF[i - 1][c] - dx;
      fa[c] = fb;
      xa[c] = xb;
    }
  }

  float vals[20];
  int nv = 0;
  for (int i = 0; i < mk; i++)
    for (int j = i; j < mk; j++) {
      float s = 0.f;
#pragma unroll
      for (int c = 0; c < 4; c++) s += dG[i][c] * dG[j][c];
      vals[nv++] = s;
    }
  for (int i = 0; i < mk; i++) {
    float s = 0.f;
#pragma unroll
    for (int c = 0; c < 4; c++) s += dG[i][c] * r[c];
    vals[nv++] = s;
  }
  for (int off = 1; off <= 32; off <<= 1)
    for (int v = 0; v < nv; v++) vals[v] += __shfl_xor(vals[v], off, 64);

  double A[5][5], bv[5], alpha[5];
  int p = 0;
  for (int i = 0; i < mk; i++)
    for (int j = i; j < mk; j++) {
      A[i][j] = (double)vals[p];
      A[j][i] = (double)vals[p];
      p++;
    }
  for (int i = 0; i < mk; i++) A[i][i] += (double)1e-4f;
  for (int i = 0; i < mk; i++) bv[i] = (double)vals[p++];

  for (int c = 0; c < mk; c++) {
    double inv = 1.0 / A[c][c];
    for (int rr = c + 1; rr < mk; rr++) {
      double fct = A[rr][c] * inv;
      for (int cc = c; cc < mk; cc++) A[rr][cc] -= fct * A[c][cc];
      bv[rr] -= fct * bv[c];
    }
  }
  for (int i = mk - 1; i >= 0; i--) {
    double s = bv[i];
    for (int j = i + 1; j < mk; j++) s -= A[i][j] * alpha[j];
    alpha[i] = s / A[i][i];
  }

#pragma unroll
  for (int c = 0; c < 4; c++) {
    float x = Fm1[c];
    for (int i = 0; i < mk; i++) x -= dF[i][c] * (float)alpha[i];
    Xw[base + 64 * c] = x;
    if (zc != nullptr) zc[b * KCAT + lane + 64 * c] = __float2bfloat16(x);
  }
}

// ---------------- host orchestration ---------------------------------------
static void eval_f(const __hip_bfloat16* zc, const __hip_bfloat16* W1b,
                   const __hip_bfloat16* W2b, const float* b1, const float* b2,
                   __hip_bfloat16* hb, float* Fout, hipStream_t stream) {
  gemm_mfma<64, 128, true><<<dim3(B_ROWS / 64, D_HID / 128), 256, 0, stream>>>(
      zc, W1b, KCAT, b1, nullptr, hb, D_HID);
  gemm_mfma<64, 64, false><<<dim3(B_ROWS / 64, D_LAT / 64), 256, 0, stream>>>(
      hb, W2b, D_HID, b2, Fout, nullptr, D_LAT);
}

extern "C" void kernel_launch(void* const* d_in, const int* in_sizes, int n_in,
                              void* d_out, int out_size, void* d_ws,
                              size_t ws_size, hipStream_t stream) {
  const float* ctx = (const float*)d_in[0];
  const float* W1 = (const float*)d_in[1];
  const float* b1 = (const float*)d_in[2];
  const float* W2 = (const float*)d_in[3];
  const float* b2 = (const float*)d_in[4];
  float* out = (float*)d_out;

  float* ws = (float*)d_ws;
  float* sig = ws;                        // 16
  float* vA = ws + 16;                    // 512
  float* vB = vA + KCAT;                  // 512
  float* uA = vB + KCAT;                  // 256
  float* uB = uA + D_LAT;                 // 256
  float* G1p = uB + D_LAT;                // 512*512
  float* G2 = G1p + KCAT * KCAT;          // 256*256
  float* T1 = G2 + D_LAT * D_LAT;         // 512*512 (Ghat^2 temp)
  float* M1 = T1 + KCAT * KCAT;           // 512*512 (Ghat^4)
  float* T2 = M1 + KCAT * KCAT;           // 256*256
  float* M2 = T2 + D_LAT * D_LAT;         // 256*256
  float* Xh = M2 + D_LAT * D_LAT;         // 7*SLOT
  float* Fh = Xh + NRING * SLOT;          // 7*SLOT
  __hip_bfloat16* W1b = (__hip_bfloat16*)(Fh + NRING * SLOT);  // 524288
  __hip_bfloat16* W2b = W1b + D_HID * KCAT;                    // 262144
  __hip_bfloat16* zc = W2b + D_LAT * D_HID;                    // 2048*512
  __hip_bfloat16* hb = zc + B_ROWS * KCAT;                     // 2048*1024
  // ~41 MB total

  // 1) init (+ x0 = 0, vA = 0, uA = 1)
  init_kernel<<<4096, 256, 0, stream>>>(ctx, zc, G1p, G2, Xh, vA, uA);
  // 2) Gram matrices + v0 = W1^T ones
  gram_kernel<<<640, 256, 0, stream>>>(W1, W2, G1p, G2);
  colsum_kernel<<<64, 256, 0, stream>>>(W1, vA);
  // 3) squarings: T = (G/8)^2 [scale 1/64], M = T^2
  sq_kernel<<<80, 256, 0, stream>>>(G1p, T1, G2, T2, 0.015625f);
  sq_kernel<<<80, 256, 0, stream>>>(T1, M1, T2, M2, 1.0f);
  // 4) joint matvec chain (8 launches):
  //    v: Ghat,Ghat,Ghat,M,M,M,M,Ghat  (v0->v20; v19 left in vB)
  //    u: M,M,M,M,M,Ghat,-,-           (u0->u21; u20 left in uB)
  {
    const float kE = 0.125f;  // Ghat scale
    const float* Pv[8] = {G1p, G1p, G1p, M1, M1, M1, M1, G1p};
    float svs[8] = {kE, kE, kE, 1.f, 1.f, 1.f, 1.f, kE};
    const float* Pu[8] = {M2, M2, M2, M2, M2, G2, nullptr, nullptr};
    float sus[8] = {1.f, 1.f, 1.f, 1.f, 1.f, kE, 0.f, 0.f};
    for (int i = 0; i < 8; i++) {
      const float* vi = (i & 1) ? vB : vA;
      float* vo = (i & 1) ? vA : vB;
      const float* ui = (i & 1) ? uB : uA;
      float* uo = (i & 1) ? uA : uB;
      mv_kernel<<<192, 256, 0, stream>>>(Pv[i], vi, vo, svs[i], Pu[i], ui, uo,
                                         sus[i], i < 6);
    }
  }
  // final: vA = v20, vB = v19, uB = u20, uA = u21
  sigma_kernel<<<1, 256, 0, stream>>>(vA, vB, uB, uA, sig);
  wfold_kernel<<<3072, 256, 0, stream>>>(W1, W2, sig, W1b, W2b);

  // F0 = f(x0)
  eval_f(zc, W1b, W2b, b1, b2, hb, Fh, stream);
  // X1 = F0; zc = bf16(F0); F1 = f(X1)
  warm1_kernel<<<SLOT / 256, 256, 0, stream>>>(Fh, Xh, zc);
  eval_f(zc, W1b, W2b, b1, b2, hb, Fh + SLOT, stream);
  // X2 = F0; F2 = F1
  warm2_kernel<<<SLOT / 256, 256, 0, stream>>>(Fh, Xh, Fh);

  // Anderson loop: t = 3..25
  for (int t = 3; t <= 25; t++) {
    int mk = (t - 1 < 5) ? (t - 1) : 5;
    float* Xw = (t == 25) ? out : (Xh + (t % NRING) * SLOT);
    __hip_bfloat16* zarg = (t == 25) ? nullptr : zc;
    anderson_step_kernel<<<B_ROWS / 4, 256, 0, stream>>>(Xh, Fh, Xw, zarg, t, mk);
    if (t < 25) {
      eval_f(zc, W1b, W2b, b1, b2, hb, Fh + (t % NRING) * SLOT, stream);
    }
  }
}